// Round 10
// baseline (1400.793 us; speedup 1.0000x reference)
//
#include <hip/hip_runtime.h>
#include <hip/hip_bf16.h>
#include <cstdint>

#define NB 32
#define NT 2000
#define TP 2048
#define NENC 1024
#define NDEC 1024
#define NATTN 512
#define NHEAD 4
#define NH 2048      // NHEAD*NATTN
#define NC 64
#define NKS 50
#define NKLEN 101
#define NPH 256
#define NPROF 101
#define NKT 32       // K tiles of 32 in the main GEMM

typedef __attribute__((ext_vector_type(8))) short bf16x8;
typedef __attribute__((ext_vector_type(4))) float f32x4;
typedef __attribute__((ext_vector_type(8))) unsigned short u16x8;

__device__ __forceinline__ void gload_lds16(const void* g, void* l) {
    __builtin_amdgcn_global_load_lds((__attribute__((address_space(1))) void*)(g),
                                     (__attribute__((address_space(3))) void*)(l), 16, 0, 0);
}

__device__ __forceinline__ unsigned short f2bf(float f) {
    unsigned u = __float_as_uint(f);
    return (unsigned short)((u + 0x7fffu + ((u >> 16) & 1u)) >> 16);
}

__device__ __forceinline__ int prof_of(int t, int len) {
    if (t < NKS) return t;
    if (t < len - NKS) return NKS;
    if (t < len) return NKS + 1 + (t - (len - NKS));
    return NKS;
}

__device__ __forceinline__ float4 f4add3(float4 a, float4 b, float4 c) {
    return make_float4(a.x + b.x + c.x, a.y + b.y + c.y, a.z + b.z + c.z, a.w + b.w + c.w);
}
__device__ __forceinline__ float4 f4fma(float s, float4 a, float4 acc) {
    return make_float4(fmaf(s, a.x, acc.x), fmaf(s, a.y, acc.y),
                       fmaf(s, a.z, acc.z), fmaf(s, a.w, acc.w));
}

// keep a 16B frag alive without MFMA consuming it (anti-DCE, rule #17)
__device__ __forceinline__ void keep(const bf16x8& x) {
    const int4 t = *(const int4*)&x;
    asm volatile("" :: "v"(t.x), "v"(t.y), "v"(t.z), "v"(t.w));
}

// ---------------- f32 -> bf16 conversion (vectorized 8/thread) ----------------
__global__ void k_convert(const float* __restrict__ src, unsigned short* __restrict__ dst, int n8) {
    int stride = gridDim.x * blockDim.x;
    for (int i = blockIdx.x * blockDim.x + threadIdx.x; i < n8; i += stride) {
        const float4* s = (const float4*)(src) + (size_t)i * 2;
        float4 x = s[0], y = s[1];
        u16x8 o;
        o[0] = f2bf(x.x); o[1] = f2bf(x.y); o[2] = f2bf(x.z); o[3] = f2bf(x.w);
        o[4] = f2bf(y.x); o[5] = f2bf(y.y); o[6] = f2bf(y.z); o[7] = f2bf(y.w);
        *((u16x8*)dst + i) = o;
    }
}

// ---------------- prefix sums of Wconv rows: wcum[hc][0..101] ----------------
__global__ void k_wcum(const float* __restrict__ Wconv, float* __restrict__ wcum) {
    int hc = threadIdx.x;  // 256 rows
    float c = 0.f;
    wcum[hc * 102] = 0.f;
    for (int k = 0; k < NKLEN; ++k) {
        c += Wconv[hc * NKLEN + k];
        wcum[hc * 102 + k + 1] = c;
    }
}

// ---------------- WlocT[c][n] = Wloc[n][c] (512 KB, one-shot) ----------------
__global__ void k_wlocT(const float* __restrict__ Wloc, float* __restrict__ wlocT) {
    int c = blockIdx.x;  // 64
    for (int n = threadIdx.x; n < NH; n += 256)
        wlocT[c * NH + n] = Wloc[(size_t)n * NC + c];
}

// ---------------- dec_h[h][b][a] = Wdec[h,a,:].dec[b,:] + bdec ----------------
__global__ void k_dech(const float* __restrict__ dec, const float* __restrict__ Wdec,
                       const float* __restrict__ bdec, float* __restrict__ dech) {
    int h = blockIdx.x >> 5, b = blockIdx.x & 31;
    __shared__ float dl[NDEC];
    int tid = threadIdx.x;
    for (int r = 0; r < 4; ++r) dl[tid + r * 256] = dec[b * NDEC + tid + r * 256];
    __syncthreads();
    for (int a2 = 0; a2 < 2; ++a2) {
        int a = tid + a2 * 256;
        const float4* wr = (const float4*)&Wdec[((size_t)(h * NATTN + a)) * NDEC];
        float acc = 0.f;
        for (int e4 = 0; e4 < NDEC / 4; ++e4) {
            float4 w4 = wr[e4];
            acc += w4.x * dl[e4 * 4] + w4.y * dl[e4 * 4 + 1] + w4.z * dl[e4 * 4 + 2] + w4.w * dl[e4 * 4 + 3];
        }
        dech[(h * NB + b) * NATTN + a] = acc + bdec[h * NATTN + a];
    }
}

// ---- add[b][p][n] = dec_h + benc + bloc + WlocT^T . conv_profile(p) ----------
__global__ void k_addprof(const float* __restrict__ wcum, const float* __restrict__ dech,
                          const float* __restrict__ benc, const float* __restrict__ bloc,
                          const float* __restrict__ wlocT, const int* __restrict__ enc_len,
                          float* __restrict__ addp) {
    int p0 = blockIdx.x * 4, b = blockIdx.y;
    int len = enc_len[b];
    __shared__ float convp[4][256];
    int tid = threadIdx.x;
    float invl = 1.f / (float)len;
#pragma unroll
    for (int pp = 0; pp < 4; ++pp) {
        int p = min(p0 + pp, NPROF - 1);
        int kmin, kmax;
        if (p < NKS)       { kmin = NKS - p; kmax = min(NKLEN, len - p + NKS); }
        else if (p == NKS) { kmin = 0;       kmax = NKLEN; }
        else               { kmin = 0;       kmax = 151 - p; }
        if (kmax < kmin) kmax = kmin;
        convp[pp][tid] = (wcum[tid * 102 + kmax] - wcum[tid * 102 + kmin]) * invl;
    }
    __syncthreads();
    int h0 = tid >> 7, h1 = 2 + h0;
    int n40 = tid, n41 = 256 + tid;   // float4 indices into the 2048-wide n dim
    const float4* dech4 = (const float4*)dech;
    const float4* benc4 = (const float4*)benc;
    const float4* bloc4 = (const float4*)bloc;
    float4 base0 = f4add3(dech4[(h0 * NB + b) * 128 + (tid & 127)], benc4[n40], bloc4[n40]);
    float4 base1 = f4add3(dech4[(h1 * NB + b) * 128 + (tid & 127)], benc4[n41], bloc4[n41]);
    float4 acc[4][2];
#pragma unroll
    for (int pp = 0; pp < 4; ++pp) { acc[pp][0] = base0; acc[pp][1] = base1; }
    const float4* wT4 = (const float4*)wlocT;
#pragma unroll 4
    for (int c = 0; c < NC; ++c) {
        float4 w0 = wT4[c * 512 + n40];
        float4 w1 = wT4[c * 512 + n41];
#pragma unroll
        for (int pp = 0; pp < 4; ++pp) {
            acc[pp][0] = f4fma(convp[pp][h0 * 64 + c], w0, acc[pp][0]);
            acc[pp][1] = f4fma(convp[pp][h1 * 64 + c], w1, acc[pp][1]);
        }
    }
    float4* addp4 = (float4*)addp;
#pragma unroll
    for (int pp = 0; pp < 4; ++pp) {
        int p = p0 + pp;
        if (p < NPROF) {
            addp4[((size_t)(b * NPROF + p)) * 512 + n40] = acc[pp][0];
            addp4[((size_t)(b * NPROF + p)) * 512 + n41] = acc[pp][1];
        }
    }
}

// ---------------- main fused GEMM body, template ablation variants ------------
// V=0 FULL (real). V=2 NODS: no staging/ds_read, const frags; barriers+MFMA+epi.
// V=3 NOMFMA: full memory pipeline (staging+vmcnt+ds_read, frags kept live),
// MFMA removed. Ablation outputs go to a scratch buffer (never read).
template<int V>
__device__ __forceinline__ void gemm_body(char* smem,
        const unsigned short* __restrict__ encbf, const unsigned short* __restrict__ wencbf,
        const float* __restrict__ addp, const float* __restrict__ wattn,
        const int* __restrict__ enc_len, float* __restrict__ sout) {
    constexpr bool STG = (V == 0 || V == 3);   // in-loop staging + counted vmcnt
    constexpr bool PSTG = (V != 2);            // prologue staging
    constexpr bool DS  = (V != 2);             // ds_read fragments
    constexpr bool MF  = (V != 3);             // MFMAs
    int bid = blockIdx.x;
    int L = (bid & 7) * 256 + (bid >> 3);   // bijective XCD-chunk swizzle (2048%8==0)
    int bx = L & 7, by = (L >> 3) & 7, b = L >> 6;
    int n0 = bx * 256, t0 = by * 256;
    int len = enc_len[b];
    if (t0 >= len) return;  // fully-masked tile
    int tid = threadIdx.x, lane = tid & 63, w = tid >> 6;
    int wr = w >> 2, wc = w & 3;
    int ro = lane & 15, g4 = lane >> 4;

    int srow = w * 32 + (lane >> 2);
    int csrc = ((lane & 3) ^ ((lane >> 3) & 3)) * 8;
    const unsigned short* Asrc0 = encbf + (size_t)b * NT * NENC + (size_t)(t0 + srow) * NENC + csrc;
    const unsigned short* Bsrc0 = wencbf + (size_t)(n0 + srow) * NENC + csrc;
    char* dA = smem + w * 2048;
    char* dB = smem + 16384 + w * 2048;

    auto STAGE_A = [&](int kt) {
        char* d = dA + ((kt & 3) << 15);
        const unsigned short* s = Asrc0 + kt * 32;
        gload_lds16(s, d);
        gload_lds16(s + 16 * NENC, d + 1024);
    };
    auto STAGE_B = [&](int kt) {
        char* d = dB + ((kt & 3) << 15);
        const unsigned short* s = Bsrc0 + kt * 32;
        gload_lds16(s, d);
        gload_lds16(s + 16 * NENC, d + 1024);
    };

    f32x4 acc[8][4] = {};
    bf16x8 aE[8], aO[8];
    bf16x8 cfrag;
#pragma unroll
    for (int i = 0; i < 8; ++i) cfrag[i] = (short)0x3f80;  // bf16 1.0 (V2 const frags)
    int swb = (g4 ^ ((ro >> 1) & 3)) * 16;
    int rdA = (wr * 128 + ro) * 64 + swb;
    int rdB = 16384 + (wc * 64 + ro) * 64 + swb;

    if constexpr (PSTG) {
        STAGE_A(0); STAGE_B(0); STAGE_A(1); STAGE_B(1); STAGE_A(2); STAGE_B(2);
        asm volatile("s_waitcnt vmcnt(8)" ::: "memory");
    }
    asm volatile("s_barrier" ::: "memory");
    if constexpr (DS) {
#pragma unroll
        for (int m = 0; m < 8; ++m) aE[m] = *(const bf16x8*)(smem + rdA + m * 1024);
        if constexpr (!MF) {
#pragma unroll
            for (int m = 0; m < 8; ++m) keep(aE[m]);
        }
    } else {
#pragma unroll
        for (int m = 0; m < 8; ++m) { aE[m] = cfrag; aO[m] = cfrag; }
    }

#define BAR asm volatile("s_barrier" ::: "memory")
#define LGKM0 { asm volatile("s_waitcnt lgkmcnt(0)" ::: "memory"); __builtin_amdgcn_sched_barrier(0); }
#define WAITVM_(N) asm volatile("s_waitcnt vmcnt(" #N ")" ::: "memory")
#define WAITVM(N) WAITVM_(N)
#define PHA(KT, AR, ST) \
    { const char* Aq = smem + (((KT) & 3) << 15); \
      bf16x8 b0, b1; \
      if constexpr (DS) { b0 = *(const bf16x8*)(Aq + rdB); b1 = *(const bf16x8*)(Aq + rdB + 1024); } \
      else { b0 = cfrag; b1 = cfrag; } \
      if constexpr (!MF) { keep(b0); keep(b1); } \
      if constexpr (STG) { if (ST) STAGE_A((KT) + 3); } \
      BAR; LGKM0; \
      if constexpr (MF) { \
        __builtin_amdgcn_s_setprio(1); \
        _Pragma("unroll") \
        for (int m = 0; m < 8; ++m) { \
            acc[m][0] = __builtin_amdgcn_mfma_f32_16x16x32_bf16(AR[m], b0, acc[m][0], 0, 0, 0); \
            acc[m][1] = __builtin_amdgcn_mfma_f32_16x16x32_bf16(AR[m], b1, acc[m][1], 0, 0, 0); } \
        __builtin_amdgcn_s_setprio(0); \
      } \
      BAR; }
#define PHB(KT, AR, AN, ST, VM, PF) \
    { if constexpr (STG) { WAITVM(VM); } \
      const char* Aq = smem + (((KT) & 3) << 15); \
      const char* Aq1 = smem + ((((KT) + 1) & 3) << 15); \
      bf16x8 b2, b3; \
      if constexpr (DS) { b2 = *(const bf16x8*)(Aq + rdB + 2048); b3 = *(const bf16x8*)(Aq + rdB + 3072); } \
      else { b2 = cfrag; b3 = cfrag; } \
      if constexpr (!MF) { keep(b2); keep(b3); } \
      if constexpr (STG) { if (ST) STAGE_B((KT) + 3); } \
      BAR; LGKM0; \
      if constexpr (DS) { \
        if (PF) { _Pragma("unroll") \
            for (int m = 0; m < 8; ++m) { AN[m] = *(const bf16x8*)(Aq1 + rdA + m * 1024); \
                if constexpr (!MF) keep(AN[m]); } } \
      } \
      if constexpr (MF) { \
        __builtin_amdgcn_s_setprio(1); \
        _Pragma("unroll") \
        for (int m = 0; m < 8; ++m) { \
            acc[m][2] = __builtin_amdgcn_mfma_f32_16x16x32_bf16(AR[m], b2, acc[m][2], 0, 0, 0); \
            acc[m][3] = __builtin_amdgcn_mfma_f32_16x16x32_bf16(AR[m], b3, acc[m][3], 0, 0, 0); } \
        __builtin_amdgcn_s_setprio(0); \
      } \
      BAR; }

#pragma unroll 1
    for (int p = 0; p < 14; ++p) {
        int k0 = 2 * p, k1 = 2 * p + 1;
        PHA(k0, aE, 1)
        PHB(k0, aE, aO, 1, 6, 1)
        PHA(k1, aO, 1)
        PHB(k1, aO, aE, 1, 6, 1)
    }
    PHA(28, aE, 1) PHB(28, aE, aO, 1, 6, 1)
    PHA(29, aO, 0) PHB(29, aO, aE, 0, 4, 1)
    PHA(30, aE, 0) PHB(30, aE, aO, 0, 0, 1)
    PHA(31, aO, 0) PHB(31, aO, aE, 0, 0, 0)
#undef PHA
#undef PHB
#undef WAITVM
#undef WAITVM_
#undef LGKM0
#undef BAR

    __builtin_amdgcn_sched_barrier(0);
    // epilogue: tanh(acc+add)*wattn, 16-lane reduce over n, atomicAdd
    int h = n0 >> 9;
    float wat[4];
#pragma unroll
    for (int n = 0; n < 4; ++n) wat[n] = wattn[n0 + wc * 64 + n * 16 + ro];
    const float* addb = addp + (size_t)b * NPROF * NH + n0 + wc * 64 + ro;
    float* sr = sout + ((size_t)(h * NB + b)) * TP;
#pragma unroll
    for (int m = 0; m < 8; ++m) {
#pragma unroll
        for (int e = 0; e < 4; ++e) {
            int t = t0 + wr * 128 + m * 16 + g4 * 4 + e;
            int tc = t < NT ? t : NT - 1;
            const float* arow = addb + (size_t)prof_of(tc, len) * NH;
            float s = 0.f;
#pragma unroll
            for (int n = 0; n < 4; ++n) {
                float v = acc[m][n][e] + arow[n * 16];
                v = fminf(fmaxf(v, -15.f), 15.f);
                float e2 = __expf(2.f * v);
                s += ((e2 - 1.f) / (e2 + 1.f)) * wat[n];
            }
            s += __shfl_xor(s, 1); s += __shfl_xor(s, 2);
            s += __shfl_xor(s, 4); s += __shfl_xor(s, 8);
            if (ro == 0) atomicAdd(&sr[t], s);
        }
    }
}

__global__ __launch_bounds__(512, 2) void k_gemm(
        const unsigned short* __restrict__ encbf, const unsigned short* __restrict__ wencbf,
        const float* __restrict__ addp, const float* __restrict__ wattn,
        const int* __restrict__ enc_len, float* __restrict__ sout) {
    extern __shared__ char smem[];
    gemm_body<0>(smem, encbf, wencbf, addp, wattn, enc_len, sout);
}
__global__ __launch_bounds__(512, 2) void k_abl_nods(
        const unsigned short* __restrict__ encbf, const unsigned short* __restrict__ wencbf,
        const float* __restrict__ addp, const float* __restrict__ wattn,
        const int* __restrict__ enc_len, float* __restrict__ sout) {
    extern __shared__ char smem[];
    gemm_body<2>(smem, encbf, wencbf, addp, wattn, enc_len, sout);
}
__global__ __launch_bounds__(512, 2) void k_abl_nomfma(
        const unsigned short* __restrict__ encbf, const unsigned short* __restrict__ wencbf,
        const float* __restrict__ addp, const float* __restrict__ wattn,
        const int* __restrict__ enc_len, float* __restrict__ sout) {
    extern __shared__ char smem[];
    gemm_body<3>(smem, encbf, wencbf, addp, wattn, enc_len, sout);
}

// ---------------- masked softmax over t per (h,b) -> attn ---------------------
__global__ void k_softmax(const float* __restrict__ scores, const int* __restrict__ enc_len,
                          float* __restrict__ attn) {
    int h = blockIdx.x >> 5, b = blockIdx.x & 31;
    int len = enc_len[b];
    int tid = threadIdx.x;
    const float* row = scores + ((size_t)(h * NB + b)) * TP;
    __shared__ float red[4];
    float m = -1e30f;
    for (int t = tid; t < len; t += 256) m = fmaxf(m, row[t]);
    for (int d = 32; d; d >>= 1) m = fmaxf(m, __shfl_xor(m, d));
    if ((tid & 63) == 0) red[tid >> 6] = m;
    __syncthreads();
    m = fmaxf(fmaxf(red[0], red[1]), fmaxf(red[2], red[3]));
    __syncthreads();
    float z = 0.f;
    for (int t = tid; t < len; t += 256) z += __expf(row[t] - m);
    for (int d = 32; d; d >>= 1) z += __shfl_xor(z, d);
    if ((tid & 63) == 0) red[tid >> 6] = z;
    __syncthreads();
    z = red[0] + red[1] + red[2] + red[3];
    float inv = 1.f / z;
    for (int t = tid; t < NT; t += 256) {
        float av = (t < len) ? __expf(row[t] - m) * inv : 0.f;
        attn[((size_t)(h * NB + b)) * NT + t] = av;
    }
}

// ---------------- attn_weight = mean over heads ------------------------------
__global__ void k_attnw(const float* __restrict__ attn, float* __restrict__ out) {
    int b = blockIdx.y;
    int t = blockIdx.x * 256 + threadIdx.x;
    if (t < NT) {
        float s = 0.f;
        for (int h = 0; h < NHEAD; ++h) s += attn[((size_t)(h * NB + b)) * NT + t];
        out[NB * 1024 + b * NT + t] = 0.25f * s;
    }
}

// ---------------- ctx partials: [ts][h][b][e] --------------------------------
__global__ void k_ctx(const float* __restrict__ enc, const float* __restrict__ attn,
                      const int* __restrict__ enc_len, float* __restrict__ ctxp) {
    int ec = blockIdx.x, ts = blockIdx.y, b = blockIdx.z;
    int tid = threadIdx.x;
    __shared__ float attnL[NHEAD][500];
    int t0 = ts * 500;
    for (int i = tid; i < NHEAD * 500; i += 256) {
        int hh = i / 500, tt = i - hh * 500;
        attnL[hh][tt] = attn[((size_t)(hh * NB + b)) * NT + t0 + tt];
    }
    __syncthreads();
    int len = enc_len[b];
    int t1 = min(t0 + 500, len);
    int e = ec * 256 + tid;
    float a0 = 0.f, a1 = 0.f, a2 = 0.f, a3 = 0.f;
    for (int t = t0; t < t1; ++t) {
        float ev = enc[((size_t)b * NT + t) * NENC + e];
        int tt = t - t0;
        a0 += attnL[0][tt] * ev; a1 += attnL[1][tt] * ev;
        a2 += attnL[2][tt] * ev; a3 += attnL[3][tt] * ev;
    }
    ctxp[(((size_t)ts * NHEAD + 0) * NB + b) * NENC + e] = a0;
    ctxp[(((size_t)ts * NHEAD + 1) * NB + b) * NENC + e] = a1;
    ctxp[(((size_t)ts * NHEAD + 2) * NB + b) * NENC + e] = a2;
    ctxp[(((size_t)ts * NHEAD + 3) * NB + b) * NENC + e] = a3;
}

// ---------------- out[h][b][o] = Wout[h,o,:].ctx + bout ----------------------
__global__ void k_out(const float* __restrict__ ctxp, const float* __restrict__ Wout,
                      const float* __restrict__ bout, float* __restrict__ out) {
    int b = blockIdx.x, h = blockIdx.y;
    int tid = threadIdx.x;
    __shared__ float ctxL[NENC];
    for (int r = 0; r < 4; ++r) {
        int e = tid + r * 256;
        float s = 0.f;
        for (int s4 = 0; s4 < 4; ++s4) s += ctxp[(((size_t)s4 * NHEAD + h) * NB + b) * NENC + e];
        ctxL[e] = s;
    }
    __syncthreads();
    int o = tid;
    float acc = bout[h * NPH + o];
    const float4* wrow = (const float4*)&Wout[((size_t)(h * NPH + o)) * NENC];
    for (int e4 = 0; e4 < NENC / 4; ++e4) {
        float4 w4 = wrow[e4];
        acc += w4.x * ctxL[e4 * 4] + w4.y * ctxL[e4 * 4 + 1] + w4.z * ctxL[e4 * 4 + 2] + w4.w * ctxL[e4 * 4 + 3];
    }
    out[b * 1024 + h * NPH + o] = acc;
}

extern "C" void kernel_launch(void* const* d_in, const int* in_sizes, int n_in,
                              void* d_out, int out_size, void* d_ws, size_t ws_size,
                              hipStream_t stream) {
    const float* enc   = (const float*)d_in[0];
    const int*   elen  = (const int*)d_in[1];
    const float* dec   = (const float*)d_in[2];
    const float* Wenc  = (const float*)d_in[3];
    const float* benc  = (const float*)d_in[4];
    const float* Wdec  = (const float*)d_in[5];
    const float* bdec  = (const float*)d_in[6];
    const float* wattn = (const float*)d_in[7];
    const float* Wconv = (const float*)d_in[8];
    const float* Wloc  = (const float*)d_in[9];
    const float* bloc  = (const float*)d_in[10];
    const float* Wout  = (const float*)d_in[11];
    const float* bout  = (const float*)d_in[12];
    float* out = (float*)d_out;

    char* ws = (char*)d_ws;
    size_t off = 0;
    auto alloc = [&](size_t bytes) { size_t o = off; off += (bytes + 255) & ~(size_t)255; return o; };
    unsigned short* encbf  = (unsigned short*)(ws + alloc((size_t)NB * NT * NENC * 2));
    unsigned short* wencbf = (unsigned short*)(ws + alloc((size_t)NH * NENC * 2));
    float* wcum  = (float*)(ws + alloc((size_t)256 * 102 * 4));
    float* wlocT = (float*)(ws + alloc((size_t)NC * NH * 4));
    float* dech  = (float*)(ws + alloc((size_t)NHEAD * NB * NATTN * 4));
    float* addp  = (float*)(ws + alloc((size_t)NB * NPROF * NH * 4));
    float* scor  = (float*)(ws + alloc((size_t)NHEAD * NB * TP * 4));
    float* attn  = (float*)(ws + alloc((size_t)NHEAD * NB * NT * 4));
    float* ctxp  = (float*)(ws + alloc((size_t)4 * NHEAD * NB * NENC * 4));
    float* dumm  = (float*)(ws + alloc((size_t)NHEAD * NB * TP * 4));  // ablation sink
    if (off > ws_size) return;  // insufficient workspace: bail (validation will flag it)

    hipFuncSetAttribute((const void*)k_gemm, hipFuncAttributeMaxDynamicSharedMemorySize, 131072);
    hipFuncSetAttribute((const void*)k_abl_nods, hipFuncAttributeMaxDynamicSharedMemorySize, 131072);
    hipFuncSetAttribute((const void*)k_abl_nomfma, hipFuncAttributeMaxDynamicSharedMemorySize, 131072);

    k_convert<<<2048, 256, 0, stream>>>(enc, encbf, NB * NT * NENC / 8);
    k_convert<<<64, 256, 0, stream>>>(Wenc, wencbf, NH * NENC / 8);
    k_wcum<<<1, 256, 0, stream>>>(Wconv, wcum);
    k_wlocT<<<64, 256, 0, stream>>>(Wloc, wlocT);
    k_dech<<<NHEAD * NB, 256, 0, stream>>>(dec, Wdec, bdec, dech);
    k_addprof<<<dim3((NPROF + 3) / 4, NB), 256, 0, stream>>>(wcum, dech, benc, bloc, wlocT, elen, addp);
    hipMemsetAsync(scor, 0, (size_t)NHEAD * NB * TP * 4, stream);
    k_gemm<<<2048, 512, 131072, stream>>>(encbf, wencbf, addp, wattn, elen, scor);
    k_softmax<<<NHEAD * NB, 256, 0, stream>>>(scor, elen, attn);
    k_attnw<<<dim3(8, NB), 256, 0, stream>>>(attn, out);
    k_ctx<<<dim3(4, 4, NB), 256, 0, stream>>>(enc, attn, elen, ctxp);
    k_out<<<dim3(NB, NHEAD), 256, 0, stream>>>(ctxp, Wout, bout, out);
    // --- ablation dispatches (diagnostic; write to scratch, never read) ---
    k_abl_nomfma<<<2048, 512, 131072, stream>>>(encbf, wencbf, addp, wattn, elen, dumm);
    k_abl_nods<<<2048, 512, 131072, stream>>>(encbf, wencbf, addp, wattn, elen, dumm);
}

// Round 11
// 790.861 us; speedup vs baseline: 1.7712x; 1.7712x over previous
//
#include <hip/hip_runtime.h>
#include <hip/hip_bf16.h>
#include <cstdint>

#define NB 32
#define NT 2000
#define TP 2048
#define NENC 1024
#define NDEC 1024
#define NATTN 512
#define NHEAD 4
#define NH 2048      // NHEAD*NATTN
#define NC 64
#define NKS 50
#define NKLEN 101
#define NPH 256
#define NPROF 101

typedef __attribute__((ext_vector_type(8))) short bf16x8;
typedef __attribute__((ext_vector_type(4))) float f32x4;
typedef __attribute__((ext_vector_type(8))) unsigned short u16x8;

__device__ __forceinline__ void gload_lds16(const void* g, void* l) {
    __builtin_amdgcn_global_load_lds((__attribute__((address_space(1))) void*)(g),
                                     (__attribute__((address_space(3))) void*)(l), 16, 0, 0);
}

__device__ __forceinline__ unsigned short f2bf(float f) {
    unsigned u = __float_as_uint(f);
    return (unsigned short)((u + 0x7fffu + ((u >> 16) & 1u)) >> 16);
}

__device__ __forceinline__ int prof_of(int t, int len) {
    if (t < NKS) return t;
    if (t < len - NKS) return NKS;
    if (t < len) return NKS + 1 + (t - (len - NKS));
    return NKS;
}

__device__ __forceinline__ float4 f4add3(float4 a, float4 b, float4 c) {
    return make_float4(a.x + b.x + c.x, a.y + b.y + c.y, a.z + b.z + c.z, a.w + b.w + c.w);
}
__device__ __forceinline__ float4 f4fma(float s, float4 a, float4 acc) {
    return make_float4(fmaf(s, a.x, acc.x), fmaf(s, a.y, acc.y),
                       fmaf(s, a.z, acc.z), fmaf(s, a.w, acc.w));
}

// ---------------- f32 -> bf16 conversion (vectorized 8/thread) ----------------
__global__ void k_convert(const float* __restrict__ src, unsigned short* __restrict__ dst, int n8) {
    int stride = gridDim.x * blockDim.x;
    for (int i = blockIdx.x * blockDim.x + threadIdx.x; i < n8; i += stride) {
        const float4* s = (const float4*)(src) + (size_t)i * 2;
        float4 x = s[0], y = s[1];
        u16x8 o;
        o[0] = f2bf(x.x); o[1] = f2bf(x.y); o[2] = f2bf(x.z); o[3] = f2bf(x.w);
        o[4] = f2bf(y.x); o[5] = f2bf(y.y); o[6] = f2bf(y.z); o[7] = f2bf(y.w);
        *((u16x8*)dst + i) = o;
    }
}

// ---------------- prefix sums of Wconv rows: wcum[hc][0..101] ----------------
__global__ void k_wcum(const float* __restrict__ Wconv, float* __restrict__ wcum) {
    int hc = threadIdx.x;  // 256 rows
    float c = 0.f;
    wcum[hc * 102] = 0.f;
    for (int k = 0; k < NKLEN; ++k) {
        c += Wconv[hc * NKLEN + k];
        wcum[hc * 102 + k + 1] = c;
    }
}

// ---------------- WlocT[c][n] = Wloc[n][c] (512 KB, one-shot) ----------------
__global__ void k_wlocT(const float* __restrict__ Wloc, float* __restrict__ wlocT) {
    int c = blockIdx.x;  // 64
    for (int n = threadIdx.x; n < NH; n += 256)
        wlocT[c * NH + n] = Wloc[(size_t)n * NC + c];
}

// ---------------- dec_h[h][b][a] = Wdec[h,a,:].dec[b,:] + bdec ----------------
__global__ void k_dech(const float* __restrict__ dec, const float* __restrict__ Wdec,
                       const float* __restrict__ bdec, float* __restrict__ dech) {
    int h = blockIdx.x >> 5, b = blockIdx.x & 31;
    __shared__ float dl[NDEC];
    int tid = threadIdx.x;
    for (int r = 0; r < 4; ++r) dl[tid + r * 256] = dec[b * NDEC + tid + r * 256];
    __syncthreads();
    for (int a2 = 0; a2 < 2; ++a2) {
        int a = tid + a2 * 256;
        const float4* wr = (const float4*)&Wdec[((size_t)(h * NATTN + a)) * NDEC];
        float acc = 0.f;
        for (int e4 = 0; e4 < NDEC / 4; ++e4) {
            float4 w4 = wr[e4];
            acc += w4.x * dl[e4 * 4] + w4.y * dl[e4 * 4 + 1] + w4.z * dl[e4 * 4 + 2] + w4.w * dl[e4 * 4 + 3];
        }
        dech[(h * NB + b) * NATTN + a] = acc + bdec[h * NATTN + a];
    }
}

// ---- add[b][p][n] = dec_h + benc + bloc + WlocT^T . conv_profile(p) ----------
__global__ void k_addprof(const float* __restrict__ wcum, const float* __restrict__ dech,
                          const float* __restrict__ benc, const float* __restrict__ bloc,
                          const float* __restrict__ wlocT, const int* __restrict__ enc_len,
                          float* __restrict__ addp) {
    int p0 = blockIdx.x * 4, b = blockIdx.y;
    int len = enc_len[b];
    __shared__ float convp[4][256];
    int tid = threadIdx.x;
    float invl = 1.f / (float)len;
#pragma unroll
    for (int pp = 0; pp < 4; ++pp) {
        int p = min(p0 + pp, NPROF - 1);
        int kmin, kmax;
        if (p < NKS)       { kmin = NKS - p; kmax = min(NKLEN, len - p + NKS); }
        else if (p == NKS) { kmin = 0;       kmax = NKLEN; }
        else               { kmin = 0;       kmax = 151 - p; }
        if (kmax < kmin) kmax = kmin;
        convp[pp][tid] = (wcum[tid * 102 + kmax] - wcum[tid * 102 + kmin]) * invl;
    }
    __syncthreads();
    int h0 = tid >> 7, h1 = 2 + h0;
    int n40 = tid, n41 = 256 + tid;   // float4 indices into the 2048-wide n dim
    const float4* dech4 = (const float4*)dech;
    const float4* benc4 = (const float4*)benc;
    const float4* bloc4 = (const float4*)bloc;
    float4 base0 = f4add3(dech4[(h0 * NB + b) * 128 + (tid & 127)], benc4[n40], bloc4[n40]);
    float4 base1 = f4add3(dech4[(h1 * NB + b) * 128 + (tid & 127)], benc4[n41], bloc4[n41]);
    float4 acc[4][2];
#pragma unroll
    for (int pp = 0; pp < 4; ++pp) { acc[pp][0] = base0; acc[pp][1] = base1; }
    const float4* wT4 = (const float4*)wlocT;
#pragma unroll 4
    for (int c = 0; c < NC; ++c) {
        float4 w0 = wT4[c * 512 + n40];
        float4 w1 = wT4[c * 512 + n41];
#pragma unroll
        for (int pp = 0; pp < 4; ++pp) {
            acc[pp][0] = f4fma(convp[pp][h0 * 64 + c], w0, acc[pp][0]);
            acc[pp][1] = f4fma(convp[pp][h1 * 64 + c], w1, acc[pp][1]);
        }
    }
    float4* addp4 = (float4*)addp;
#pragma unroll
    for (int pp = 0; pp < 4; ++pp) {
        int p = p0 + pp;
        if (p < NPROF) {
            addp4[((size_t)(b * NPROF + p)) * 512 + n40] = acc[pp][0];
            addp4[((size_t)(b * NPROF + p)) * 512 + n41] = acc[pp][1];
        }
    }
}

// ---------------- main fused GEMM + tanh + wattn-reduce -> scores -------------
// v3: 4-wave blocks (256 thr), block tile 256t x 128n, wave tile 128x64
// (per-wave code identical to the proven R6 kernel). 2-deep LDS ring of
// 24 KB (A 16K + B 8K) = 48 KB total -> TWO blocks co-resident per CU
// (the R6 128KB ring capped residency at 1 block/CU = the measured ~240us
// exposed-stall component C). One __syncthreads per kt; stages for kt+1
// issue before reads+MFMA of kt, so the drain is cheap and the partner
// block hides the rest. Same chunk-XOR swizzle (bank-conflict-free).
__global__ __launch_bounds__(256, 2) void k_gemm(
        const unsigned short* __restrict__ encbf, const unsigned short* __restrict__ wencbf,
        const float* __restrict__ addp, const float* __restrict__ wattn,
        const int* __restrict__ enc_len, float* __restrict__ scores) {
    extern __shared__ char smem[];
    int bid = blockIdx.x;
    int L = (bid & 7) * 512 + (bid >> 3);   // bijective XCD swizzle (4096%8==0)
    int nt = L & 15, ty = (L >> 4) & 7, b = L >> 7;
    int n0 = nt * 128, t0 = ty * 256;
    int len = enc_len[b];
    if (t0 >= len) return;  // fully-masked tile
    int tid = threadIdx.x, lane = tid & 63, w = tid >> 6;  // w in 0..3
    int wr = w >> 1, wc = w & 1;
    int ro = lane & 15, g4 = lane >> 4;

    // staging: lane -> row (lane>>2) within 16-row group, 16B chunk (lane&3);
    // source chunk pre-XOR'd by (row>>1)&3 so linear LDS + swizzled read works.
    int lrow = lane >> 2;
    int csrc = ((lane & 3) ^ ((lane >> 3) & 3)) * 8;   // elements
    const unsigned short* aB = encbf + (size_t)b * NT * NENC;
    int rA[4], rB[2];
#pragma unroll
    for (int g = 0; g < 4; ++g) { int t = t0 + w * 64 + g * 16 + lrow; rA[g] = t < NT ? t : NT - 1; }
#pragma unroll
    for (int g = 0; g < 2; ++g) rB[g] = n0 + w * 32 + g * 16 + lrow;

    auto STAGE = [&](int q, int kt) {
        char* base = smem + q * 24576;
        int k0 = kt * 32 + csrc;
#pragma unroll
        for (int g = 0; g < 4; ++g)
            gload_lds16(aB + (size_t)rA[g] * NENC + k0, base + w * 4096 + g * 1024);
#pragma unroll
        for (int g = 0; g < 2; ++g)
            gload_lds16(wencbf + (size_t)rB[g] * NENC + k0, base + 16384 + w * 2048 + g * 1024);
    };

    f32x4 acc[8][4] = {};
    int swb = (g4 ^ ((ro >> 1) & 3)) * 16;               // swizzled chunk byte on read
    int rdA = (wr * 128 + ro) * 64 + swb;                 // + m*1024
    int rdB = 16384 + (wc * 64 + ro) * 64 + swb;          // + n*1024

    STAGE(0, 0);
    __syncthreads();
#pragma unroll 2
    for (int kt = 0; kt < 32; ++kt) {
        int q = kt & 1;
        if (kt < 31) STAGE(q ^ 1, kt + 1);
        const char* base = smem + q * 24576;
        bf16x8 A[8], Bf[4];
#pragma unroll
        for (int m = 0; m < 8; ++m) A[m] = *(const bf16x8*)(base + rdA + m * 1024);
#pragma unroll
        for (int n = 0; n < 4; ++n) Bf[n] = *(const bf16x8*)(base + rdB + n * 1024);
        __builtin_amdgcn_s_setprio(1);
#pragma unroll
        for (int m = 0; m < 8; ++m) {
            acc[m][0] = __builtin_amdgcn_mfma_f32_16x16x32_bf16(A[m], Bf[0], acc[m][0], 0, 0, 0);
            acc[m][1] = __builtin_amdgcn_mfma_f32_16x16x32_bf16(A[m], Bf[1], acc[m][1], 0, 0, 0);
            acc[m][2] = __builtin_amdgcn_mfma_f32_16x16x32_bf16(A[m], Bf[2], acc[m][2], 0, 0, 0);
            acc[m][3] = __builtin_amdgcn_mfma_f32_16x16x32_bf16(A[m], Bf[3], acc[m][3], 0, 0, 0);
        }
        __builtin_amdgcn_s_setprio(0);
        __syncthreads();   // own stages (issued before reads+MFMA) drained + barrier
    }

    // epilogue: tanh(acc+add)*wattn, 16-lane reduce over n, atomicAdd to scores
    int h = n0 >> 9;
    float wat[4];
#pragma unroll
    for (int n = 0; n < 4; ++n) wat[n] = wattn[n0 + wc * 64 + n * 16 + ro];
    const float* addb = addp + (size_t)b * NPROF * NH + n0 + wc * 64 + ro;
    float* sr = scores + ((size_t)(h * NB + b)) * TP;
#pragma unroll
    for (int m = 0; m < 8; ++m) {
#pragma unroll
        for (int e = 0; e < 4; ++e) {
            int t = t0 + wr * 128 + m * 16 + g4 * 4 + e;
            int tc = t < NT ? t : NT - 1;
            const float* arow = addb + (size_t)prof_of(tc, len) * NH;
            float s = 0.f;
#pragma unroll
            for (int n = 0; n < 4; ++n) {
                float v = acc[m][n][e] + arow[n * 16];
                v = fminf(fmaxf(v, -15.f), 15.f);
                float e2 = __expf(2.f * v);
                s += ((e2 - 1.f) / (e2 + 1.f)) * wat[n];
            }
            s += __shfl_xor(s, 1); s += __shfl_xor(s, 2);
            s += __shfl_xor(s, 4); s += __shfl_xor(s, 8);
            if (ro == 0) atomicAdd(&sr[t], s);
        }
    }
}

// ---------------- masked softmax over t per (h,b) -> attn ---------------------
__global__ void k_softmax(const float* __restrict__ scores, const int* __restrict__ enc_len,
                          float* __restrict__ attn) {
    int h = blockIdx.x >> 5, b = blockIdx.x & 31;
    int len = enc_len[b];
    int tid = threadIdx.x;
    const float* row = scores + ((size_t)(h * NB + b)) * TP;
    __shared__ float red[4];
    float m = -1e30f;
    for (int t = tid; t < len; t += 256) m = fmaxf(m, row[t]);
    for (int d = 32; d; d >>= 1) m = fmaxf(m, __shfl_xor(m, d));
    if ((tid & 63) == 0) red[tid >> 6] = m;
    __syncthreads();
    m = fmaxf(fmaxf(red[0], red[1]), fmaxf(red[2], red[3]));
    __syncthreads();
    float z = 0.f;
    for (int t = tid; t < len; t += 256) z += __expf(row[t] - m);
    for (int d = 32; d; d >>= 1) z += __shfl_xor(z, d);
    if ((tid & 63) == 0) red[tid >> 6] = z;
    __syncthreads();
    z = red[0] + red[1] + red[2] + red[3];
    float inv = 1.f / z;
    for (int t = tid; t < NT; t += 256) {
        float av = (t < len) ? __expf(row[t] - m) * inv : 0.f;
        attn[((size_t)(h * NB + b)) * NT + t] = av;
    }
}

// ---------------- attn_weight = mean over heads ------------------------------
__global__ void k_attnw(const float* __restrict__ attn, float* __restrict__ out) {
    int b = blockIdx.y;
    int t = blockIdx.x * 256 + threadIdx.x;
    if (t < NT) {
        float s = 0.f;
        for (int h = 0; h < NHEAD; ++h) s += attn[((size_t)(h * NB + b)) * NT + t];
        out[NB * 1024 + b * NT + t] = 0.25f * s;
    }
}

// ---------------- ctx partials: [ts][h][b][e] --------------------------------
__global__ void k_ctx(const float* __restrict__ enc, const float* __restrict__ attn,
                      const int* __restrict__ enc_len, float* __restrict__ ctxp) {
    int ec = blockIdx.x, ts = blockIdx.y, b = blockIdx.z;
    int tid = threadIdx.x;
    __shared__ float attnL[NHEAD][500];
    int t0 = ts * 500;
    for (int i = tid; i < NHEAD * 500; i += 256) {
        int hh = i / 500, tt = i - hh * 500;
        attnL[hh][tt] = attn[((size_t)(hh * NB + b)) * NT + t0 + tt];
    }
    __syncthreads();
    int len = enc_len[b];
    int t1 = min(t0 + 500, len);
    int e = ec * 256 + tid;
    float a0 = 0.f, a1 = 0.f, a2 = 0.f, a3 = 0.f;
    for (int t = t0; t < t1; ++t) {
        float ev = enc[((size_t)b * NT + t) * NENC + e];
        int tt = t - t0;
        a0 += attnL[0][tt] * ev; a1 += attnL[1][tt] * ev;
        a2 += attnL[2][tt] * ev; a3 += attnL[3][tt] * ev;
    }
    ctxp[(((size_t)ts * NHEAD + 0) * NB + b) * NENC + e] = a0;
    ctxp[(((size_t)ts * NHEAD + 1) * NB + b) * NENC + e] = a1;
    ctxp[(((size_t)ts * NHEAD + 2) * NB + b) * NENC + e] = a2;
    ctxp[(((size_t)ts * NHEAD + 3) * NB + b) * NENC + e] = a3;
}

// ---------------- out[h][b][o] = Wout[h,o,:].ctx + bout ----------------------
__global__ void k_out(const float* __restrict__ ctxp, const float* __restrict__ Wout,
                      const float* __restrict__ bout, float* __restrict__ out) {
    int b = blockIdx.x, h = blockIdx.y;
    int tid = threadIdx.x;
    __shared__ float ctxL[NENC];
    for (int r = 0; r < 4; ++r) {
        int e = tid + r * 256;
        float s = 0.f;
        for (int s4 = 0; s4 < 4; ++s4) s += ctxp[(((size_t)s4 * NHEAD + h) * NB + b) * NENC + e];
        ctxL[e] = s;
    }
    __syncthreads();
    int o = tid;
    float acc = bout[h * NPH + o];
    const float4* wrow = (const float4*)&Wout[((size_t)(h * NPH + o)) * NENC];
    for (int e4 = 0; e4 < NENC / 4; ++e4) {
        float4 w4 = wrow[e4];
        acc += w4.x * ctxL[e4 * 4] + w4.y * ctxL[e4 * 4 + 1] + w4.z * ctxL[e4 * 4 + 2] + w4.w * ctxL[e4 * 4 + 3];
    }
    out[b * 1024 + h * NPH + o] = acc;
}

extern "C" void kernel_launch(void* const* d_in, const int* in_sizes, int n_in,
                              void* d_out, int out_size, void* d_ws, size_t ws_size,
                              hipStream_t stream) {
    const float* enc   = (const float*)d_in[0];
    const int*   elen  = (const int*)d_in[1];
    const float* dec   = (const float*)d_in[2];
    const float* Wenc  = (const float*)d_in[3];
    const float* benc  = (const float*)d_in[4];
    const float* Wdec  = (const float*)d_in[5];
    const float* bdec  = (const float*)d_in[6];
    const float* wattn = (const float*)d_in[7];
    const float* Wconv = (const float*)d_in[8];
    const float* Wloc  = (const float*)d_in[9];
    const float* bloc  = (const float*)d_in[10];
    const float* Wout  = (const float*)d_in[11];
    const float* bout  = (const float*)d_in[12];
    float* out = (float*)d_out;

    char* ws = (char*)d_ws;
    size_t off = 0;
    auto alloc = [&](size_t bytes) { size_t o = off; off += (bytes + 255) & ~(size_t)255; return o; };
    unsigned short* encbf  = (unsigned short*)(ws + alloc((size_t)NB * NT * NENC * 2));
    unsigned short* wencbf = (unsigned short*)(ws + alloc((size_t)NH * NENC * 2));
    float* wcum  = (float*)(ws + alloc((size_t)256 * 102 * 4));
    float* wlocT = (float*)(ws + alloc((size_t)NC * NH * 4));
    float* dech  = (float*)(ws + alloc((size_t)NHEAD * NB * NATTN * 4));
    float* addp  = (float*)(ws + alloc((size_t)NB * NPROF * NH * 4));
    float* scor  = (float*)(ws + alloc((size_t)NHEAD * NB * TP * 4));
    float* attn  = (float*)(ws + alloc((size_t)NHEAD * NB * NT * 4));
    float* ctxp  = (float*)(ws + alloc((size_t)4 * NHEAD * NB * NENC * 4));
    if (off > ws_size) return;  // insufficient workspace: bail (validation will flag it)

    hipFuncSetAttribute((const void*)k_gemm, hipFuncAttributeMaxDynamicSharedMemorySize, 49152);

    k_convert<<<2048, 256, 0, stream>>>(enc, encbf, NB * NT * NENC / 8);
    k_convert<<<64, 256, 0, stream>>>(Wenc, wencbf, NH * NENC / 8);
    k_wcum<<<1, 256, 0, stream>>>(Wconv, wcum);
    k_wlocT<<<64, 256, 0, stream>>>(Wloc, wlocT);
    k_dech<<<NHEAD * NB, 256, 0, stream>>>(dec, Wdec, bdec, dech);
    k_addprof<<<dim3((NPROF + 3) / 4, NB), 256, 0, stream>>>(wcum, dech, benc, bloc, wlocT, elen, addp);
    hipMemsetAsync(scor, 0, (size_t)NHEAD * NB * TP * 4, stream);
    k_gemm<<<4096, 256, 49152, stream>>>(encbf, wencbf, addp, wattn, elen, scor);
    k_softmax<<<NHEAD * NB, 256, 0, stream>>>(scor, elen, attn);
    k_attnw<<<dim3(8, NB), 256, 0, stream>>>(attn, out);
    k_ctx<<<dim3(4, 4, NB), 256, 0, stream>>>(enc, attn, elen, ctxp);
    k_out<<<dim3(NB, NHEAD), 256, 0, stream>>>(ctxp, Wout, bout, out);
}

// Round 12
// 732.056 us; speedup vs baseline: 1.9135x; 1.0803x over previous
//
#include <hip/hip_runtime.h>
#include <hip/hip_bf16.h>
#include <cstdint>

#define NB 32
#define NT 2000
#define TP 2048
#define NENC 1024
#define NDEC 1024
#define NATTN 512
#define NHEAD 4
#define NH 2048      // NHEAD*NATTN
#define NC 64
#define NKS 50
#define NKLEN 101
#define NPH 256
#define NPROF 101

typedef __attribute__((ext_vector_type(8))) short bf16x8;
typedef __attribute__((ext_vector_type(4))) float f32x4;
typedef __attribute__((ext_vector_type(8))) unsigned short u16x8;

__device__ __forceinline__ void gload_lds16(const void* g, void* l) {
    __builtin_amdgcn_global_load_lds((__attribute__((address_space(1))) void*)(g),
                                     (__attribute__((address_space(3))) void*)(l), 16, 0, 0);
}

__device__ __forceinline__ unsigned short f2bf(float f) {
    unsigned u = __float_as_uint(f);
    return (unsigned short)((u + 0x7fffu + ((u >> 16) & 1u)) >> 16);
}

__device__ __forceinline__ int prof_of(int t, int len) {
    if (t < NKS) return t;
    if (t < len - NKS) return NKS;
    if (t < len) return NKS + 1 + (t - (len - NKS));
    return NKS;
}

__device__ __forceinline__ float4 f4add3(float4 a, float4 b, float4 c) {
    return make_float4(a.x + b.x + c.x, a.y + b.y + c.y, a.z + b.z + c.z, a.w + b.w + c.w);
}
__device__ __forceinline__ float4 f4fma(float s, float4 a, float4 acc) {
    return make_float4(fmaf(s, a.x, acc.x), fmaf(s, a.y, acc.y),
                       fmaf(s, a.z, acc.z), fmaf(s, a.w, acc.w));
}

// ---------------- f32 -> bf16 conversion (vectorized 8/thread) ----------------
__global__ void k_convert(const float* __restrict__ src, unsigned short* __restrict__ dst, int n8) {
    int stride = gridDim.x * blockDim.x;
    for (int i = blockIdx.x * blockDim.x + threadIdx.x; i < n8; i += stride) {
        const float4* s = (const float4*)(src) + (size_t)i * 2;
        float4 x = s[0], y = s[1];
        u16x8 o;
        o[0] = f2bf(x.x); o[1] = f2bf(x.y); o[2] = f2bf(x.z); o[3] = f2bf(x.w);
        o[4] = f2bf(y.x); o[5] = f2bf(y.y); o[6] = f2bf(y.z); o[7] = f2bf(y.w);
        *((u16x8*)dst + i) = o;
    }
}

// ---------------- prefix sums of Wconv rows: wcum[hc][0..101] ----------------
__global__ void k_wcum(const float* __restrict__ Wconv, float* __restrict__ wcum) {
    int hc = threadIdx.x;  // 256 rows
    float c = 0.f;
    wcum[hc * 102] = 0.f;
    for (int k = 0; k < NKLEN; ++k) {
        c += Wconv[hc * NKLEN + k];
        wcum[hc * 102 + k + 1] = c;
    }
}

// ---------------- WlocT[c][n] = Wloc[n][c] (512 KB, one-shot) ----------------
__global__ void k_wlocT(const float* __restrict__ Wloc, float* __restrict__ wlocT) {
    int c = blockIdx.x;  // 64
    for (int n = threadIdx.x; n < NH; n += 256)
        wlocT[c * NH + n] = Wloc[(size_t)n * NC + c];
}

// ---------------- dec_h[h][b][a] = Wdec[h,a,:].dec[b,:] + bdec ----------------
__global__ void k_dech(const float* __restrict__ dec, const float* __restrict__ Wdec,
                       const float* __restrict__ bdec, float* __restrict__ dech) {
    int h = blockIdx.x >> 5, b = blockIdx.x & 31;
    __shared__ float dl[NDEC];
    int tid = threadIdx.x;
    for (int r = 0; r < 4; ++r) dl[tid + r * 256] = dec[b * NDEC + tid + r * 256];
    __syncthreads();
    for (int a2 = 0; a2 < 2; ++a2) {
        int a = tid + a2 * 256;
        const float4* wr = (const float4*)&Wdec[((size_t)(h * NATTN + a)) * NDEC];
        float acc = 0.f;
        for (int e4 = 0; e4 < NDEC / 4; ++e4) {
            float4 w4 = wr[e4];
            acc += w4.x * dl[e4 * 4] + w4.y * dl[e4 * 4 + 1] + w4.z * dl[e4 * 4 + 2] + w4.w * dl[e4 * 4 + 3];
        }
        dech[(h * NB + b) * NATTN + a] = acc + bdec[h * NATTN + a];
    }
}

// ---- add[b][p][n] = dec_h + benc + bloc + WlocT^T . conv_profile(p) ----------
__global__ void k_addprof(const float* __restrict__ wcum, const float* __restrict__ dech,
                          const float* __restrict__ benc, const float* __restrict__ bloc,
                          const float* __restrict__ wlocT, const int* __restrict__ enc_len,
                          float* __restrict__ addp) {
    int p0 = blockIdx.x * 4, b = blockIdx.y;
    int len = enc_len[b];
    __shared__ float convp[4][256];
    int tid = threadIdx.x;
    float invl = 1.f / (float)len;
#pragma unroll
    for (int pp = 0; pp < 4; ++pp) {
        int p = min(p0 + pp, NPROF - 1);
        int kmin, kmax;
        if (p < NKS)       { kmin = NKS - p; kmax = min(NKLEN, len - p + NKS); }
        else if (p == NKS) { kmin = 0;       kmax = NKLEN; }
        else               { kmin = 0;       kmax = 151 - p; }
        if (kmax < kmin) kmax = kmin;
        convp[pp][tid] = (wcum[tid * 102 + kmax] - wcum[tid * 102 + kmin]) * invl;
    }
    __syncthreads();
    int h0 = tid >> 7, h1 = 2 + h0;
    int n40 = tid, n41 = 256 + tid;   // float4 indices into the 2048-wide n dim
    const float4* dech4 = (const float4*)dech;
    const float4* benc4 = (const float4*)benc;
    const float4* bloc4 = (const float4*)bloc;
    float4 base0 = f4add3(dech4[(h0 * NB + b) * 128 + (tid & 127)], benc4[n40], bloc4[n40]);
    float4 base1 = f4add3(dech4[(h1 * NB + b) * 128 + (tid & 127)], benc4[n41], bloc4[n41]);
    float4 acc[4][2];
#pragma unroll
    for (int pp = 0; pp < 4; ++pp) { acc[pp][0] = base0; acc[pp][1] = base1; }
    const float4* wT4 = (const float4*)wlocT;
#pragma unroll 4
    for (int c = 0; c < NC; ++c) {
        float4 w0 = wT4[c * 512 + n40];
        float4 w1 = wT4[c * 512 + n41];
#pragma unroll
        for (int pp = 0; pp < 4; ++pp) {
            acc[pp][0] = f4fma(convp[pp][h0 * 64 + c], w0, acc[pp][0]);
            acc[pp][1] = f4fma(convp[pp][h1 * 64 + c], w1, acc[pp][1]);
        }
    }
    float4* addp4 = (float4*)addp;
#pragma unroll
    for (int pp = 0; pp < 4; ++pp) {
        int p = p0 + pp;
        if (p < NPROF) {
            addp4[((size_t)(b * NPROF + p)) * 512 + n40] = acc[pp][0];
            addp4[((size_t)(b * NPROF + p)) * 512 + n41] = acc[pp][1];
        }
    }
}

// ---------------- main fused GEMM + tanh + wattn-reduce -> scores -------------
// v4: 128x128 block tile, 4 waves (wave tile 64x64, acc[4][4] = 64 AGPR),
// 2-deep 16KB ring = 32 KB LDS, __launch_bounds__(256,3) -> 3 waves/SIMD,
// 3 blocks/CU co-resident (~37% occupancy). Tests the last untested cell:
// conflict-free LDS x high occupancy. Same chunk-XOR swizzle and one
// __syncthreads per kt (stages for kt+1 issued before reads+MFMA of kt).
__global__ __launch_bounds__(256, 3) void k_gemm(
        const unsigned short* __restrict__ encbf, const unsigned short* __restrict__ wencbf,
        const float* __restrict__ addp, const float* __restrict__ wattn,
        const int* __restrict__ enc_len, float* __restrict__ scores) {
    extern __shared__ char smem[];
    int bid = blockIdx.x;
    int L = (bid & 7) * 1024 + (bid >> 3);   // bijective XCD swizzle (8192%8==0)
    int nt = L & 15, ty = (L >> 4) & 15, b = L >> 8;
    int n0 = nt * 128, t0 = ty * 128;
    int len = enc_len[b];
    if (t0 >= len) return;  // fully-masked tile
    int tid = threadIdx.x, lane = tid & 63, w = tid >> 6;  // w in 0..3
    int wr = w >> 1, wc = w & 1;
    int ro = lane & 15, g4 = lane >> 4;

    // staging: lane -> row (lane>>2) within a 16-row group, 16B chunk (lane&3);
    // source chunk pre-XOR'd by ((row%16)>>1)&3 so linear LDS dest + swizzled
    // read are consistent (gload_lds dest must be uniform+lane*16).
    int lrow = lane >> 2;
    int csrc = ((lane & 3) ^ ((lane >> 3) & 3)) * 8;   // elements
    const unsigned short* aB = encbf + (size_t)b * NT * NENC;
    int rA[2], rB[2];
#pragma unroll
    for (int g = 0; g < 2; ++g) { int t = t0 + g * 64 + w * 16 + lrow; rA[g] = t < NT ? t : NT - 1; }
#pragma unroll
    for (int g = 0; g < 2; ++g) rB[g] = n0 + g * 64 + w * 16 + lrow;

    auto STAGE = [&](int q, int kt) {
        char* base = smem + q * 16384;
        int k0 = kt * 32 + csrc;
#pragma unroll
        for (int g = 0; g < 2; ++g)
            gload_lds16(aB + (size_t)rA[g] * NENC + k0, base + g * 4096 + w * 1024);
#pragma unroll
        for (int g = 0; g < 2; ++g)
            gload_lds16(wencbf + (size_t)rB[g] * NENC + k0, base + 8192 + g * 4096 + w * 1024);
    };

    f32x4 acc[4][4] = {};
    int swb = (g4 ^ ((ro >> 1) & 3)) * 16;               // swizzled chunk byte on read
    int rdA = (wr * 64 + ro) * 64 + swb;                  // + m*1024
    int rdB = 8192 + (wc * 64 + ro) * 64 + swb;           // + n*1024

    STAGE(0, 0);
    __syncthreads();
#pragma unroll 2
    for (int kt = 0; kt < 32; ++kt) {
        int q = kt & 1;
        if (kt < 31) STAGE(q ^ 1, kt + 1);
        const char* base = smem + q * 16384;
        bf16x8 A[4], Bf[4];
#pragma unroll
        for (int m = 0; m < 4; ++m) A[m] = *(const bf16x8*)(base + rdA + m * 1024);
#pragma unroll
        for (int n = 0; n < 4; ++n) Bf[n] = *(const bf16x8*)(base + rdB + n * 1024);
        __builtin_amdgcn_s_setprio(1);
#pragma unroll
        for (int m = 0; m < 4; ++m) {
            acc[m][0] = __builtin_amdgcn_mfma_f32_16x16x32_bf16(A[m], Bf[0], acc[m][0], 0, 0, 0);
            acc[m][1] = __builtin_amdgcn_mfma_f32_16x16x32_bf16(A[m], Bf[1], acc[m][1], 0, 0, 0);
            acc[m][2] = __builtin_amdgcn_mfma_f32_16x16x32_bf16(A[m], Bf[2], acc[m][2], 0, 0, 0);
            acc[m][3] = __builtin_amdgcn_mfma_f32_16x16x32_bf16(A[m], Bf[3], acc[m][3], 0, 0, 0);
        }
        __builtin_amdgcn_s_setprio(0);
        __syncthreads();   // own stages (issued before reads+MFMA) drained + barrier
    }

    // epilogue: tanh(acc+add)*wattn, 16-lane reduce over n, atomicAdd to scores
    int h = n0 >> 9;
    float wat[4];
#pragma unroll
    for (int n = 0; n < 4; ++n) wat[n] = wattn[n0 + wc * 64 + n * 16 + ro];
    const float* addb = addp + (size_t)b * NPROF * NH + n0 + wc * 64 + ro;
    float* sr = scores + ((size_t)(h * NB + b)) * TP;
#pragma unroll
    for (int m = 0; m < 4; ++m) {
#pragma unroll
        for (int e = 0; e < 4; ++e) {
            int t = t0 + wr * 64 + m * 16 + g4 * 4 + e;
            int tc = t < NT ? t : NT - 1;
            const float* arow = addb + (size_t)prof_of(tc, len) * NH;
            float s = 0.f;
#pragma unroll
            for (int n = 0; n < 4; ++n) {
                float v = acc[m][n][e] + arow[n * 16];
                v = fminf(fmaxf(v, -15.f), 15.f);
                float e2 = __expf(2.f * v);
                s += ((e2 - 1.f) / (e2 + 1.f)) * wat[n];
            }
            s += __shfl_xor(s, 1); s += __shfl_xor(s, 2);
            s += __shfl_xor(s, 4); s += __shfl_xor(s, 8);
            if (ro == 0 && t < NT) atomicAdd(&sr[t], s);
        }
    }
}

// ---------------- masked softmax over t per (h,b) -> attn ---------------------
__global__ void k_softmax(const float* __restrict__ scores, const int* __restrict__ enc_len,
                          float* __restrict__ attn) {
    int h = blockIdx.x >> 5, b = blockIdx.x & 31;
    int len = enc_len[b];
    int tid = threadIdx.x;
    const float* row = scores + ((size_t)(h * NB + b)) * TP;
    __shared__ float red[4];
    float m = -1e30f;
    for (int t = tid; t < len; t += 256) m = fmaxf(m, row[t]);
    for (int d = 32; d; d >>= 1) m = fmaxf(m, __shfl_xor(m, d));
    if ((tid & 63) == 0) red[tid >> 6] = m;
    __syncthreads();
    m = fmaxf(fmaxf(red[0], red[1]), fmaxf(red[2], red[3]));
    __syncthreads();
    float z = 0.f;
    for (int t = tid; t < len; t += 256) z += __expf(row[t] - m);
    for (int d = 32; d; d >>= 1) z += __shfl_xor(z, d);
    if ((tid & 63) == 0) red[tid >> 6] = z;
    __syncthreads();
    z = red[0] + red[1] + red[2] + red[3];
    float inv = 1.f / z;
    for (int t = tid; t < NT; t += 256) {
        float av = (t < len) ? __expf(row[t] - m) * inv : 0.f;
        attn[((size_t)(h * NB + b)) * NT + t] = av;
    }
}

// ---------------- attn_weight = mean over heads ------------------------------
__global__ void k_attnw(const float* __restrict__ attn, float* __restrict__ out) {
    int b = blockIdx.y;
    int t = blockIdx.x * 256 + threadIdx.x;
    if (t < NT) {
        float s = 0.f;
        for (int h = 0; h < NHEAD; ++h) s += attn[((size_t)(h * NB + b)) * NT + t];
        out[NB * 1024 + b * NT + t] = 0.25f * s;
    }
}

// ---------------- ctx partials: [ts][h][b][e] --------------------------------
__global__ void k_ctx(const float* __restrict__ enc, const float* __restrict__ attn,
                      const int* __restrict__ enc_len, float* __restrict__ ctxp) {
    int ec = blockIdx.x, ts = blockIdx.y, b = blockIdx.z;
    int tid = threadIdx.x;
    __shared__ float attnL[NHEAD][500];
    int t0 = ts * 500;
    for (int i = tid; i < NHEAD * 500; i += 256) {
        int hh = i / 500, tt = i - hh * 500;
        attnL[hh][tt] = attn[((size_t)(hh * NB + b)) * NT + t0 + tt];
    }
    __syncthreads();
    int len = enc_len[b];
    int t1 = min(t0 + 500, len);
    int e = ec * 256 + tid;
    float a0 = 0.f, a1 = 0.f, a2 = 0.f, a3 = 0.f;
    for (int t = t0; t < t1; ++t) {
        float ev = enc[((size_t)b * NT + t) * NENC + e];
        int tt = t - t0;
        a0 += attnL[0][tt] * ev; a1 += attnL[1][tt] * ev;
        a2 += attnL[2][tt] * ev; a3 += attnL[3][tt] * ev;
    }
    ctxp[(((size_t)ts * NHEAD + 0) * NB + b) * NENC + e] = a0;
    ctxp[(((size_t)ts * NHEAD + 1) * NB + b) * NENC + e] = a1;
    ctxp[(((size_t)ts * NHEAD + 2) * NB + b) * NENC + e] = a2;
    ctxp[(((size_t)ts * NHEAD + 3) * NB + b) * NENC + e] = a3;
}

// ---------------- out[h][b][o] = Wout[h,o,:].ctx + bout ----------------------
__global__ void k_out(const float* __restrict__ ctxp, const float* __restrict__ Wout,
                      const float* __restrict__ bout, float* __restrict__ out) {
    int b = blockIdx.x, h = blockIdx.y;
    int tid = threadIdx.x;
    __shared__ float ctxL[NENC];
    for (int r = 0; r < 4; ++r) {
        int e = tid + r * 256;
        float s = 0.f;
        for (int s4 = 0; s4 < 4; ++s4) s += ctxp[(((size_t)s4 * NHEAD + h) * NB + b) * NENC + e];
        ctxL[e] = s;
    }
    __syncthreads();
    int o = tid;
    float acc = bout[h * NPH + o];
    const float4* wrow = (const float4*)&Wout[((size_t)(h * NPH + o)) * NENC];
    for (int e4 = 0; e4 < NENC / 4; ++e4) {
        float4 w4 = wrow[e4];
        acc += w4.x * ctxL[e4 * 4] + w4.y * ctxL[e4 * 4 + 1] + w4.z * ctxL[e4 * 4 + 2] + w4.w * ctxL[e4 * 4 + 3];
    }
    out[b * 1024 + h * NPH + o] = acc;
}

extern "C" void kernel_launch(void* const* d_in, const int* in_sizes, int n_in,
                              void* d_out, int out_size, void* d_ws, size_t ws_size,
                              hipStream_t stream) {
    const float* enc   = (const float*)d_in[0];
    const int*   elen  = (const int*)d_in[1];
    const float* dec   = (const float*)d_in[2];
    const float* Wenc  = (const float*)d_in[3];
    const float* benc  = (const float*)d_in[4];
    const float* Wdec  = (const float*)d_in[5];
    const float* bdec  = (const float*)d_in[6];
    const float* wattn = (const float*)d_in[7];
    const float* Wconv = (const float*)d_in[8];
    const float* Wloc  = (const float*)d_in[9];
    const float* bloc  = (const float*)d_in[10];
    const float* Wout  = (const float*)d_in[11];
    const float* bout  = (const float*)d_in[12];
    float* out = (float*)d_out;

    char* ws = (char*)d_ws;
    size_t off = 0;
    auto alloc = [&](size_t bytes) { size_t o = off; off += (bytes + 255) & ~(size_t)255; return o; };
    unsigned short* encbf  = (unsigned short*)(ws + alloc((size_t)NB * NT * NENC * 2));
    unsigned short* wencbf = (unsigned short*)(ws + alloc((size_t)NH * NENC * 2));
    float* wcum  = (float*)(ws + alloc((size_t)256 * 102 * 4));
    float* wlocT = (float*)(ws + alloc((size_t)NC * NH * 4));
    float* dech  = (float*)(ws + alloc((size_t)NHEAD * NB * NATTN * 4));
    float* addp  = (float*)(ws + alloc((size_t)NB * NPROF * NH * 4));
    float* scor  = (float*)(ws + alloc((size_t)NHEAD * NB * TP * 4));
    float* attn  = (float*)(ws + alloc((size_t)NHEAD * NB * NT * 4));
    float* ctxp  = (float*)(ws + alloc((size_t)4 * NHEAD * NB * NENC * 4));
    if (off > ws_size) return;  // insufficient workspace: bail (validation will flag it)

    hipFuncSetAttribute((const void*)k_gemm, hipFuncAttributeMaxDynamicSharedMemorySize, 32768);

    k_convert<<<2048, 256, 0, stream>>>(enc, encbf, NB * NT * NENC / 8);
    k_convert<<<64, 256, 0, stream>>>(Wenc, wencbf, NH * NENC / 8);
    k_wcum<<<1, 256, 0, stream>>>(Wconv, wcum);
    k_wlocT<<<64, 256, 0, stream>>>(Wloc, wlocT);
    k_dech<<<NHEAD * NB, 256, 0, stream>>>(dec, Wdec, bdec, dech);
    k_addprof<<<dim3((NPROF + 3) / 4, NB), 256, 0, stream>>>(wcum, dech, benc, bloc, wlocT, elen, addp);
    hipMemsetAsync(scor, 0, (size_t)NHEAD * NB * TP * 4, stream);
    k_gemm<<<8192, 256, 32768, stream>>>(encbf, wencbf, addp, wattn, elen, scor);
    k_softmax<<<NHEAD * NB, 256, 0, stream>>>(scor, elen, attn);
    k_attnw<<<dim3(8, NB), 256, 0, stream>>>(attn, out);
    k_ctx<<<dim3(4, 4, NB), 256, 0, stream>>>(enc, attn, elen, ctxp);
    k_out<<<dim3(NB, NHEAD), 256, 0, stream>>>(ctxp, Wout, bout, out);
}

// Round 13
// 670.226 us; speedup vs baseline: 2.0900x; 1.0923x over previous
//
#include <hip/hip_runtime.h>
#include <hip/hip_bf16.h>
#include <cstdint>

#define NB 32
#define NT 2000
#define TP 2048
#define NENC 1024
#define NDEC 1024
#define NATTN 512
#define NHEAD 4
#define NH 2048      // NHEAD*NATTN
#define NC 64
#define NKS 50
#define NKLEN 101
#define NPH 256
#define NPROF 101

typedef __attribute__((ext_vector_type(8))) short bf16x8;
typedef __attribute__((ext_vector_type(4))) float f32x4;
typedef __attribute__((ext_vector_type(8))) unsigned short u16x8;

__device__ __forceinline__ void gload_lds16(const void* g, void* l) {
    __builtin_amdgcn_global_load_lds((__attribute__((address_space(1))) void*)(g),
                                     (__attribute__((address_space(3))) void*)(l), 16, 0, 0);
}

__device__ __forceinline__ unsigned short f2bf(float f) {
    unsigned u = __float_as_uint(f);
    return (unsigned short)((u + 0x7fffu + ((u >> 16) & 1u)) >> 16);
}

__device__ __forceinline__ float bf2f(unsigned short u) {
    return __uint_as_float((unsigned)u << 16);
}

__device__ __forceinline__ int prof_of(int t, int len) {
    if (t < NKS) return t;
    if (t < len - NKS) return NKS;
    if (t < len) return NKS + 1 + (t - (len - NKS));
    return NKS;
}

__device__ __forceinline__ float4 f4add3(float4 a, float4 b, float4 c) {
    return make_float4(a.x + b.x + c.x, a.y + b.y + c.y, a.z + b.z + c.z, a.w + b.w + c.w);
}
__device__ __forceinline__ float4 f4fma(float s, float4 a, float4 acc) {
    return make_float4(fmaf(s, a.x, acc.x), fmaf(s, a.y, acc.y),
                       fmaf(s, a.z, acc.z), fmaf(s, a.w, acc.w));
}

// ---------------- f32 -> bf16 conversion (vectorized 8/thread) ----------------
__global__ void k_convert(const float* __restrict__ src, unsigned short* __restrict__ dst, int n8) {
    int stride = gridDim.x * blockDim.x;
    for (int i = blockIdx.x * blockDim.x + threadIdx.x; i < n8; i += stride) {
        const float4* s = (const float4*)(src) + (size_t)i * 2;
        float4 x = s[0], y = s[1];
        u16x8 o;
        o[0] = f2bf(x.x); o[1] = f2bf(x.y); o[2] = f2bf(x.z); o[3] = f2bf(x.w);
        o[4] = f2bf(y.x); o[5] = f2bf(y.y); o[6] = f2bf(y.z); o[7] = f2bf(y.w);
        *((u16x8*)dst + i) = o;
    }
}

// ---------------- prefix sums of Wconv rows: wcum[hc][0..101] ----------------
__global__ void k_wcum(const float* __restrict__ Wconv, float* __restrict__ wcum) {
    int hc = threadIdx.x;  // 256 rows
    float c = 0.f;
    wcum[hc * 102] = 0.f;
    for (int k = 0; k < NKLEN; ++k) {
        c += Wconv[hc * NKLEN + k];
        wcum[hc * 102 + k + 1] = c;
    }
}

// ---------------- WlocT[c][n] = Wloc[n][c] (512 KB, one-shot) ----------------
__global__ void k_wlocT(const float* __restrict__ Wloc, float* __restrict__ wlocT) {
    int c = blockIdx.x;  // 64
    for (int n = threadIdx.x; n < NH; n += 256)
        wlocT[c * NH + n] = Wloc[(size_t)n * NC + c];
}

// ---------------- dec_h[h][b][a] = Wdec[h,a,:].dec[b,:] + bdec ----------------
__global__ void k_dech(const float* __restrict__ dec, const float* __restrict__ Wdec,
                       const float* __restrict__ bdec, float* __restrict__ dech) {
    int h = blockIdx.x >> 5, b = blockIdx.x & 31;
    __shared__ float dl[NDEC];
    int tid = threadIdx.x;
    for (int r = 0; r < 4; ++r) dl[tid + r * 256] = dec[b * NDEC + tid + r * 256];
    __syncthreads();
    for (int a2 = 0; a2 < 2; ++a2) {
        int a = tid + a2 * 256;
        const float4* wr = (const float4*)&Wdec[((size_t)(h * NATTN + a)) * NDEC];
        float acc = 0.f;
        for (int e4 = 0; e4 < NDEC / 4; ++e4) {
            float4 w4 = wr[e4];
            acc += w4.x * dl[e4 * 4] + w4.y * dl[e4 * 4 + 1] + w4.z * dl[e4 * 4 + 2] + w4.w * dl[e4 * 4 + 3];
        }
        dech[(h * NB + b) * NATTN + a] = acc + bdec[h * NATTN + a];
    }
}

// ---- add[b][p][n] = dec_h + benc + bloc + WlocT^T . conv_profile(p) ----------
__global__ void k_addprof(const float* __restrict__ wcum, const float* __restrict__ dech,
                          const float* __restrict__ benc, const float* __restrict__ bloc,
                          const float* __restrict__ wlocT, const int* __restrict__ enc_len,
                          float* __restrict__ addp) {
    int p0 = blockIdx.x * 4, b = blockIdx.y;
    int len = enc_len[b];
    __shared__ float convp[4][256];
    int tid = threadIdx.x;
    float invl = 1.f / (float)len;
#pragma unroll
    for (int pp = 0; pp < 4; ++pp) {
        int p = min(p0 + pp, NPROF - 1);
        int kmin, kmax;
        if (p < NKS)       { kmin = NKS - p; kmax = min(NKLEN, len - p + NKS); }
        else if (p == NKS) { kmin = 0;       kmax = NKLEN; }
        else               { kmin = 0;       kmax = 151 - p; }
        if (kmax < kmin) kmax = kmin;
        convp[pp][tid] = (wcum[tid * 102 + kmax] - wcum[tid * 102 + kmin]) * invl;
    }
    __syncthreads();
    int h0 = tid >> 7, h1 = 2 + h0;
    int n40 = tid, n41 = 256 + tid;   // float4 indices into the 2048-wide n dim
    const float4* dech4 = (const float4*)dech;
    const float4* benc4 = (const float4*)benc;
    const float4* bloc4 = (const float4*)bloc;
    float4 base0 = f4add3(dech4[(h0 * NB + b) * 128 + (tid & 127)], benc4[n40], bloc4[n40]);
    float4 base1 = f4add3(dech4[(h1 * NB + b) * 128 + (tid & 127)], benc4[n41], bloc4[n41]);
    float4 acc[4][2];
#pragma unroll
    for (int pp = 0; pp < 4; ++pp) { acc[pp][0] = base0; acc[pp][1] = base1; }
    const float4* wT4 = (const float4*)wlocT;
#pragma unroll 4
    for (int c = 0; c < NC; ++c) {
        float4 w0 = wT4[c * 512 + n40];
        float4 w1 = wT4[c * 512 + n41];
#pragma unroll
        for (int pp = 0; pp < 4; ++pp) {
            acc[pp][0] = f4fma(convp[pp][h0 * 64 + c], w0, acc[pp][0]);
            acc[pp][1] = f4fma(convp[pp][h1 * 64 + c], w1, acc[pp][1]);
        }
    }
    float4* addp4 = (float4*)addp;
#pragma unroll
    for (int pp = 0; pp < 4; ++pp) {
        int p = p0 + pp;
        if (p < NPROF) {
            addp4[((size_t)(b * NPROF + p)) * 512 + n40] = acc[pp][0];
            addp4[((size_t)(b * NPROF + p)) * 512 + n41] = acc[pp][1];
        }
    }
}

// ---------------- main fused GEMM + tanh + wattn-reduce -> scores -------------
// v5: identical to the proven v4 (128x128 block tile, 4 waves, 64x64 wave
// tile, 2-deep 16KB ring, chunk-XOR swizzle, one __syncthreads per kt) with
// __launch_bounds__(256, 4): 128 regs/wave is exactly the 4-waves/SIMD
// boundary -> 4 blocks/CU (50% occupancy). v4's 3 blocks/CU gave -73us; this
// tests one more occupancy notch.
__global__ __launch_bounds__(256, 4) void k_gemm(
        const unsigned short* __restrict__ encbf, const unsigned short* __restrict__ wencbf,
        const float* __restrict__ addp, const float* __restrict__ wattn,
        const int* __restrict__ enc_len, float* __restrict__ scores) {
    extern __shared__ char smem[];
    int bid = blockIdx.x;
    int L = (bid & 7) * 1024 + (bid >> 3);   // bijective XCD swizzle (8192%8==0)
    int nt = L & 15, ty = (L >> 4) & 15, b = L >> 8;
    int n0 = nt * 128, t0 = ty * 128;
    int len = enc_len[b];
    if (t0 >= len) return;  // fully-masked tile
    int tid = threadIdx.x, lane = tid & 63, w = tid >> 6;  // w in 0..3
    int wr = w >> 1, wc = w & 1;
    int ro = lane & 15, g4 = lane >> 4;

    int lrow = lane >> 2;
    int csrc = ((lane & 3) ^ ((lane >> 3) & 3)) * 8;   // elements
    const unsigned short* aB = encbf + (size_t)b * NT * NENC;
    int rA[2], rB[2];
#pragma unroll
    for (int g = 0; g < 2; ++g) { int t = t0 + g * 64 + w * 16 + lrow; rA[g] = t < NT ? t : NT - 1; }
#pragma unroll
    for (int g = 0; g < 2; ++g) rB[g] = n0 + g * 64 + w * 16 + lrow;

    auto STAGE = [&](int q, int kt) {
        char* base = smem + q * 16384;
        int k0 = kt * 32 + csrc;
#pragma unroll
        for (int g = 0; g < 2; ++g)
            gload_lds16(aB + (size_t)rA[g] * NENC + k0, base + g * 4096 + w * 1024);
#pragma unroll
        for (int g = 0; g < 2; ++g)
            gload_lds16(wencbf + (size_t)rB[g] * NENC + k0, base + 8192 + g * 4096 + w * 1024);
    };

    f32x4 acc[4][4] = {};
    int swb = (g4 ^ ((ro >> 1) & 3)) * 16;               // swizzled chunk byte on read
    int rdA = (wr * 64 + ro) * 64 + swb;                  // + m*1024
    int rdB = 8192 + (wc * 64 + ro) * 64 + swb;           // + n*1024

    STAGE(0, 0);
    __syncthreads();
#pragma unroll 2
    for (int kt = 0; kt < 32; ++kt) {
        int q = kt & 1;
        if (kt < 31) STAGE(q ^ 1, kt + 1);
        const char* base = smem + q * 16384;
        bf16x8 A[4], Bf[4];
#pragma unroll
        for (int m = 0; m < 4; ++m) A[m] = *(const bf16x8*)(base + rdA + m * 1024);
#pragma unroll
        for (int n = 0; n < 4; ++n) Bf[n] = *(const bf16x8*)(base + rdB + n * 1024);
        __builtin_amdgcn_s_setprio(1);
#pragma unroll
        for (int m = 0; m < 4; ++m) {
            acc[m][0] = __builtin_amdgcn_mfma_f32_16x16x32_bf16(A[m], Bf[0], acc[m][0], 0, 0, 0);
            acc[m][1] = __builtin_amdgcn_mfma_f32_16x16x32_bf16(A[m], Bf[1], acc[m][1], 0, 0, 0);
            acc[m][2] = __builtin_amdgcn_mfma_f32_16x16x32_bf16(A[m], Bf[2], acc[m][2], 0, 0, 0);
            acc[m][3] = __builtin_amdgcn_mfma_f32_16x16x32_bf16(A[m], Bf[3], acc[m][3], 0, 0, 0);
        }
        __builtin_amdgcn_s_setprio(0);
        __syncthreads();
    }

    // epilogue: tanh(acc+add)*wattn, 16-lane reduce over n, atomicAdd to scores
    int h = n0 >> 9;
    float wat[4];
#pragma unroll
    for (int n = 0; n < 4; ++n) wat[n] = wattn[n0 + wc * 64 + n * 16 + ro];
    const float* addb = addp + (size_t)b * NPROF * NH + n0 + wc * 64 + ro;
    float* sr = scores + ((size_t)(h * NB + b)) * TP;
#pragma unroll
    for (int m = 0; m < 4; ++m) {
#pragma unroll
        for (int e = 0; e < 4; ++e) {
            int t = t0 + wr * 64 + m * 16 + g4 * 4 + e;
            int tc = t < NT ? t : NT - 1;
            const float* arow = addb + (size_t)prof_of(tc, len) * NH;
            float s = 0.f;
#pragma unroll
            for (int n = 0; n < 4; ++n) {
                float v = acc[m][n][e] + arow[n * 16];
                v = fminf(fmaxf(v, -15.f), 15.f);
                float e2 = __expf(2.f * v);
                s += ((e2 - 1.f) / (e2 + 1.f)) * wat[n];
            }
            s += __shfl_xor(s, 1); s += __shfl_xor(s, 2);
            s += __shfl_xor(s, 4); s += __shfl_xor(s, 8);
            if (ro == 0 && t < NT) atomicAdd(&sr[t], s);
        }
    }
}

// ---------------- masked softmax over t per (h,b) -> attn ---------------------
__global__ void k_softmax(const float* __restrict__ scores, const int* __restrict__ enc_len,
                          float* __restrict__ attn) {
    int h = blockIdx.x >> 5, b = blockIdx.x & 31;
    int len = enc_len[b];
    int tid = threadIdx.x;
    const float* row = scores + ((size_t)(h * NB + b)) * TP;
    __shared__ float red[4];
    float m = -1e30f;
    for (int t = tid; t < len; t += 256) m = fmaxf(m, row[t]);
    for (int d = 32; d; d >>= 1) m = fmaxf(m, __shfl_xor(m, d));
    if ((tid & 63) == 0) red[tid >> 6] = m;
    __syncthreads();
    m = fmaxf(fmaxf(red[0], red[1]), fmaxf(red[2], red[3]));
    __syncthreads();
    float z = 0.f;
    for (int t = tid; t < len; t += 256) z += __expf(row[t] - m);
    for (int d = 32; d; d >>= 1) z += __shfl_xor(z, d);
    if ((tid & 63) == 0) red[tid >> 6] = z;
    __syncthreads();
    z = red[0] + red[1] + red[2] + red[3];
    float inv = 1.f / z;
    for (int t = tid; t < NT; t += 256) {
        float av = (t < len) ? __expf(row[t] - m) * inv : 0.f;
        attn[((size_t)(h * NB + b)) * NT + t] = av;
    }
}

// ---------------- attn_weight = mean over heads ------------------------------
__global__ void k_attnw(const float* __restrict__ attn, float* __restrict__ out) {
    int b = blockIdx.y;
    int t = blockIdx.x * 256 + threadIdx.x;
    if (t < NT) {
        float s = 0.f;
        for (int h = 0; h < NHEAD; ++h) s += attn[((size_t)(h * NB + b)) * NT + t];
        out[NB * 1024 + b * NT + t] = 0.25f * s;
    }
}

// ---------------- ctx partials: [ts][h][b][e] (bf16 enc, 2 e/thread) ----------
__global__ void k_ctx(const unsigned short* __restrict__ encbf, const float* __restrict__ attn,
                      const int* __restrict__ enc_len, float* __restrict__ ctxp) {
    int ec = blockIdx.x, ts = blockIdx.y, b = blockIdx.z;
    int tid = threadIdx.x;
    __shared__ float attnL[NHEAD][500];
    int t0 = ts * 500;
    for (int i = tid; i < NHEAD * 500; i += 256) {
        int hh = i / 500, tt = i - hh * 500;
        attnL[hh][tt] = attn[((size_t)(hh * NB + b)) * NT + t0 + tt];
    }
    __syncthreads();
    int len = enc_len[b];
    int t1 = min(t0 + 500, len);
    int e0 = ec * 512 + tid * 2;
    const unsigned* erow = (const unsigned*)(encbf + (size_t)b * NT * NENC);
    float a0x = 0.f, a0y = 0.f, a1x = 0.f, a1y = 0.f;
    float a2x = 0.f, a2y = 0.f, a3x = 0.f, a3y = 0.f;
    for (int t = t0; t < t1; ++t) {
        unsigned pv = erow[((size_t)t * NENC + e0) >> 1];
        float ex = bf2f((unsigned short)(pv & 0xffff));
        float ey = bf2f((unsigned short)(pv >> 16));
        int tt = t - t0;
        float w0 = attnL[0][tt], w1 = attnL[1][tt], w2 = attnL[2][tt], w3 = attnL[3][tt];
        a0x = fmaf(w0, ex, a0x); a0y = fmaf(w0, ey, a0y);
        a1x = fmaf(w1, ex, a1x); a1y = fmaf(w1, ey, a1y);
        a2x = fmaf(w2, ex, a2x); a2y = fmaf(w2, ey, a2y);
        a3x = fmaf(w3, ex, a3x); a3y = fmaf(w3, ey, a3y);
    }
    float2* c0 = (float2*)&ctxp[(((size_t)ts * NHEAD + 0) * NB + b) * NENC + e0];
    float2* c1 = (float2*)&ctxp[(((size_t)ts * NHEAD + 1) * NB + b) * NENC + e0];
    float2* c2 = (float2*)&ctxp[(((size_t)ts * NHEAD + 2) * NB + b) * NENC + e0];
    float2* c3 = (float2*)&ctxp[(((size_t)ts * NHEAD + 3) * NB + b) * NENC + e0];
    *c0 = make_float2(a0x, a0y);
    *c1 = make_float2(a1x, a1y);
    *c2 = make_float2(a2x, a2y);
    *c3 = make_float2(a3x, a3y);
}

// ---------------- out[h][b][o] = Wout[h,o,:].ctx + bout ----------------------
__global__ void k_out(const float* __restrict__ ctxp, const float* __restrict__ Wout,
                      const float* __restrict__ bout, float* __restrict__ out) {
    int b = blockIdx.x, h = blockIdx.y;
    int tid = threadIdx.x;
    __shared__ float ctxL[NENC];
    for (int r = 0; r < 4; ++r) {
        int e = tid + r * 256;
        float s = 0.f;
        for (int s4 = 0; s4 < 4; ++s4) s += ctxp[(((size_t)s4 * NHEAD + h) * NB + b) * NENC + e];
        ctxL[e] = s;
    }
    __syncthreads();
    int o = tid;
    float acc = bout[h * NPH + o];
    const float4* wrow = (const float4*)&Wout[((size_t)(h * NPH + o)) * NENC];
    for (int e4 = 0; e4 < NENC / 4; ++e4) {
        float4 w4 = wrow[e4];
        acc += w4.x * ctxL[e4 * 4] + w4.y * ctxL[e4 * 4 + 1] + w4.z * ctxL[e4 * 4 + 2] + w4.w * ctxL[e4 * 4 + 3];
    }
    out[b * 1024 + h * NPH + o] = acc;
}

extern "C" void kernel_launch(void* const* d_in, const int* in_sizes, int n_in,
                              void* d_out, int out_size, void* d_ws, size_t ws_size,
                              hipStream_t stream) {
    const float* enc   = (const float*)d_in[0];
    const int*   elen  = (const int*)d_in[1];
    const float* dec   = (const float*)d_in[2];
    const float* Wenc  = (const float*)d_in[3];
    const float* benc  = (const float*)d_in[4];
    const float* Wdec  = (const float*)d_in[5];
    const float* bdec  = (const float*)d_in[6];
    const float* wattn = (const float*)d_in[7];
    const float* Wconv = (const float*)d_in[8];
    const float* Wloc  = (const float*)d_in[9];
    const float* bloc  = (const float*)d_in[10];
    const float* Wout  = (const float*)d_in[11];
    const float* bout  = (const float*)d_in[12];
    float* out = (float*)d_out;

    char* ws = (char*)d_ws;
    size_t off = 0;
    auto alloc = [&](size_t bytes) { size_t o = off; off += (bytes + 255) & ~(size_t)255; return o; };
    unsigned short* encbf  = (unsigned short*)(ws + alloc((size_t)NB * NT * NENC * 2));
    unsigned short* wencbf = (unsigned short*)(ws + alloc((size_t)NH * NENC * 2));
    float* wcum  = (float*)(ws + alloc((size_t)256 * 102 * 4));
    float* wlocT = (float*)(ws + alloc((size_t)NC * NH * 4));
    float* dech  = (float*)(ws + alloc((size_t)NHEAD * NB * NATTN * 4));
    float* addp  = (float*)(ws + alloc((size_t)NB * NPROF * NH * 4));
    float* scor  = (float*)(ws + alloc((size_t)NHEAD * NB * TP * 4));
    float* attn  = (float*)(ws + alloc((size_t)NHEAD * NB * NT * 4));
    float* ctxp  = (float*)(ws + alloc((size_t)4 * NHEAD * NB * NENC * 4));
    if (off > ws_size) return;  // insufficient workspace: bail (validation will flag it)

    hipFuncSetAttribute((const void*)k_gemm, hipFuncAttributeMaxDynamicSharedMemorySize, 32768);

    k_convert<<<2048, 256, 0, stream>>>(enc, encbf, NB * NT * NENC / 8);
    k_convert<<<64, 256, 0, stream>>>(Wenc, wencbf, NH * NENC / 8);
    k_wcum<<<1, 256, 0, stream>>>(Wconv, wcum);
    k_wlocT<<<64, 256, 0, stream>>>(Wloc, wlocT);
    k_dech<<<NHEAD * NB, 256, 0, stream>>>(dec, Wdec, bdec, dech);
    k_addprof<<<dim3((NPROF + 3) / 4, NB), 256, 0, stream>>>(wcum, dech, benc, bloc, wlocT, elen, addp);
    hipMemsetAsync(scor, 0, (size_t)NHEAD * NB * TP * 4, stream);
    k_gemm<<<8192, 256, 32768, stream>>>(encbf, wencbf, addp, wattn, elen, scor);
    k_softmax<<<NHEAD * NB, 256, 0, stream>>>(scor, elen, attn);
    k_attnw<<<dim3(8, NB), 256, 0, stream>>>(attn, out);
    k_ctx<<<dim3(2, 4, NB), 256, 0, stream>>>(encbf, attn, elen, ctxp);
    k_out<<<dim3(NB, NHEAD), 256, 0, stream>>>(ctxp, Wout, bout, out);
}